// Round 11
// baseline (211.179 us; speedup 1.0000x reference)
//
#include <hip/hip_runtime.h>
#include <hip/hip_bf16.h>
#include <type_traits>

// MultiHeadAttention fwd, MI355X/gfx950.
// Pipeline (bf16 MFMA, fp32 accum):
//   1. cast weights fp32->bf16 (wq scaled by ALPHA = 0.125*log2e)
//   2. merged projection GEMM: A staged as fp32 via global_load_lds (all-DMA,
//      counted vmcnt(6), cvt-on-read), B bf16 DMA: qp, kp, vpT
//   3. flash attention: cross-tile PV pipeline + mfma-lsum + literal-offset
//      unroll-2 loop. NOTE: lacc[0] is already the FULL key-sum (ones-MFMA sums
//      all k; rows identical across half-lanes) -> inv = 1/lacc[0], NO pcomb.
//   4. out = ao@wo^T+bo (fp32), 64x128-tile counted-vmcnt GEMM, 768 blocks

typedef __attribute__((ext_vector_type(8)))  __bf16 bf16x8;
typedef __attribute__((ext_vector_type(4)))  __bf16 bf16x4;
typedef __attribute__((ext_vector_type(4)))  float  f32x4;
typedef __attribute__((ext_vector_type(16))) float  f32x16;
typedef __attribute__((ext_vector_type(2)))  unsigned u32x2;
typedef __attribute__((ext_vector_type(4)))  unsigned u32x4;

#define NH  12
#define HD  64
#define DM  768
#define SEQ 2048
#define NB  4
#define M8  8192   // NB*SEQ
#define ALPHA 0.18033688011112043f  // 0.125 * log2(e): softmax scale in exp2 domain

__device__ __forceinline__ f32x4 mfma16(bf16x8 a, bf16x8 b, f32x4 c) {
  return __builtin_amdgcn_mfma_f32_16x16x32_bf16(a, b, c, 0, 0, 0);
}
__device__ __forceinline__ f32x16 mfma32(bf16x8 a, bf16x8 b, f32x16 c) {
  return __builtin_amdgcn_mfma_f32_32x32x16_bf16(a, b, c, 0, 0, 0);
}
__device__ __forceinline__ void gload16(const void* g, void* l) {
  auto gp = (__attribute__((address_space(1))) void*)(const_cast<void*>(g));
  auto lp = (__attribute__((address_space(3))) void*)(l);
  __builtin_amdgcn_global_load_lds(gp, lp, 16, 0, 0);
}
// raw v_exp_f32 (2^x). OCML exp2f's denorm path cost ~24us (rounds 4/5).
__device__ __forceinline__ float exp2_(float x) {
#if __has_builtin(__builtin_amdgcn_exp2f)
  return __builtin_amdgcn_exp2f(x);
#else
  return exp2f(x);
#endif
}

// counted waits + raw barrier
#define VMW(n) do { asm volatile("s_waitcnt vmcnt(" #n ")" ::: "memory"); \
                    __builtin_amdgcn_sched_barrier(0); } while (0)
#define BARX do { __builtin_amdgcn_s_barrier(); \
                  __builtin_amdgcn_sched_barrier(0); } while (0)

// lane-pair (l <-> l^32) half swap. r[0]=new_vdst, r[1]=new_vsrc.
__device__ __forceinline__ u32x2 pswap(unsigned a, unsigned b) {
#if __has_builtin(__builtin_amdgcn_permlane32_swap)
  return __builtin_amdgcn_permlane32_swap(a, b, false, false);
#else
  u32x2 r;
  unsigned sa = (unsigned)__shfl_xor((int)a, 32), sb = (unsigned)__shfl_xor((int)b, 32);
  int hi = ((int)threadIdx.x >> 5) & 1;
  r[0] = hi ? sb : a;
  r[1] = hi ? b : sa;
  return r;
#endif
}
// pack two f32 -> one u32 of 2 bf16 (lo in low half); compiler fuses to cvt_pk.
__device__ __forceinline__ unsigned pk(float lo, float hi_) {
  unsigned short ua = __builtin_bit_cast(unsigned short, (__bf16)lo);
  unsigned short ub = __builtin_bit_cast(unsigned short, (__bf16)hi_);
  return ((unsigned)ub << 16) | ua;
}

// ---------------- weight cast (wq pre-scaled by ALPHA) ----------------
__global__ void cast4_kernel(const float* __restrict__ a, const float* __restrict__ b,
                             const float* __restrict__ c, const float* __restrict__ d,
                             __bf16* __restrict__ oa, __bf16* __restrict__ ob,
                             __bf16* __restrict__ oc, __bf16* __restrict__ od, int n4) {
  int y = blockIdx.y;
  const float* in = y == 0 ? a : y == 1 ? b : y == 2 ? c : d;
  __bf16* out     = y == 0 ? oa : y == 1 ? ob : y == 2 ? oc : od;
  const float sc  = y == 0 ? ALPHA : 1.0f;
  int i = blockIdx.x * 256 + threadIdx.x;
  if (i < n4) {
    float4 v = ((const float4*)in)[i];
    bf16x4 r;
    r[0] = (__bf16)(v.x * sc); r[1] = (__bf16)(v.y * sc);
    r[2] = (__bf16)(v.z * sc); r[3] = (__bf16)(v.w * sc);
    ((bf16x4*)out)[i] = r;
  }
}

// ---------------- projection GEMM: C = A_f32[M8,DM] * B[DM,DM]^T + bscale*bias ----
// All-DMA staging: A fp32 via gload_lds (16KB/step, source XOR-swizzled per 16B
// chunk: c ^= row&7), B bf16 via gload_lds (8KB/step).
// A frags: 2 swizzled ds_read_b128 (fp32) + 4 cvt_pk per m -> bf16x8.
// LDS (bytes): A0@0 A1@16384 B0@32768 B1@40960  (48KB, 3 blocks/CU).
// Counted vmcnt(6) (6 DMA/step/wave), two-barrier K-loop, no drain in loop.
__device__ __forceinline__ void proj_body(const float* __restrict__ A,
                                          const __bf16* __restrict__ B,
                                          const float* __restrict__ bias,
                                          __bf16* __restrict__ C,
                                          long m0, long n0, float bscale, bool trans) {
  __shared__ __align__(16) char LDSG[49152];
  const int tid = threadIdx.x;
  const int w = tid >> 6, l = tid & 63;
  const int g = l >> 4, i16 = l & 15;
  const int wr = w >> 1, wc = w & 1;

  // A staging: lane covers row w*8 + (l>>3) (+j*32), 16B chunk l&7; src pre-swizzled
  const int schA = (l & 7) ^ ((l >> 3) & 7);
  const float* Ag = A + (m0 + w * 8 + (l >> 3)) * (long)DM + schA * 4;
  // B staging (proven scheme)
  const int srowB = l >> 2;
  const int swcB = (l & 3) ^ ((srowB >> 1) & 3);
  const __bf16* Bg = B + (n0 + 16 * w + srowB) * (long)DM + swcB * 8;

  // A frag read ptrs: row R = wr*64 + m*16 + i16 (R&7 == i16&7), chunk (2g)^rsw
  const int rsw = i16 & 7;
  const char* pA0 = LDSG + (wr * 64 + i16) * 128 + (((2 * g) ^ rsw) * 16);
  const char* pA1 = LDSG + (wr * 64 + i16) * 128 + ((((2 * g) ^ rsw) ^ 1) * 16);
  // B frag ptr
  const char* fB = LDSG + 32768 + (wc * 64 + i16) * 64 + (g ^ ((i16 >> 1) & 3)) * 16;

  f32x4 acc[4][4] = {};
  long kk0 = 0;

#define PSTAGE(SA, SB2) do { \
    _Pragma("unroll") for (int j = 0; j < 4; ++j) \
      gload16(Ag + (long)j * 32 * DM + kk0, LDSG + (SA) + (j * 32 + w * 8) * 128); \
    gload16(Bg + kk0, LDSG + 32768 + (SB2) + w * 1024); \
    gload16(Bg + 64 * (long)DM + kk0, LDSG + 32768 + (SB2) + w * 1024 + 4096); \
    kk0 += 32; } while (0)

#define PCOMP(SA, SB2) do { \
    bf16x8 af[4], bfr[4]; \
    _Pragma("unroll") for (int m = 0; m < 4; ++m) { \
      f32x4 lo = *(const f32x4*)(pA0 + (SA) + m * 2048); \
      f32x4 hh = *(const f32x4*)(pA1 + (SA) + m * 2048); \
      u32x4 u; \
      u[0] = pk(lo[0], lo[1]); u[1] = pk(lo[2], lo[3]); \
      u[2] = pk(hh[0], hh[1]); u[3] = pk(hh[2], hh[3]); \
      af[m] = __builtin_bit_cast(bf16x8, u); \
    } \
    _Pragma("unroll") for (int n = 0; n < 4; ++n) \
      bfr[n] = *(const bf16x8*)(fB + (SB2) + n * 1024); \
    __builtin_amdgcn_s_setprio(1); \
    _Pragma("unroll") for (int m = 0; m < 4; ++m) \
      _Pragma("unroll") for (int n = 0; n < 4; ++n) \
        acc[m][n] = mfma16(af[m], bfr[n], acc[m][n]); \
    __builtin_amdgcn_s_setprio(0); } while (0)

  PSTAGE(0, 0); PSTAGE(16384, 8192);
#pragma unroll 1
  for (int j2 = 0; j2 < 11; ++j2) {
    VMW(6); BARX; PCOMP(0, 0);         BARX; PSTAGE(0, 0);
    VMW(6); BARX; PCOMP(16384, 8192);  BARX; PSTAGE(16384, 8192);
  }
  VMW(6); BARX; PCOMP(0, 0);          // step 22
  VMW(0); BARX; PCOMP(16384, 8192);   // step 23
#undef PSTAGE
#undef PCOMP

  if (trans) {
#pragma unroll
    for (int m = 0; m < 4; ++m)
#pragma unroll
      for (int n = 0; n < 4; ++n) {
        const long col = n0 + wc * 64 + n * 16 + i16;
        const float bv = bias[col] * bscale;
        const long row0 = m0 + wr * 64 + m * 16 + g * 4;
        bf16x4 v4;
#pragma unroll
        for (int r = 0; r < 4; ++r) v4[r] = (__bf16)(acc[m][n][r] + bv);
        *(bf16x4*)(C + col * (long)M8 + row0) = v4;
      }
  } else {
#pragma unroll
    for (int m = 0; m < 4; ++m)
#pragma unroll
      for (int n = 0; n < 4; ++n) {
        const long col = n0 + wc * 64 + n * 16 + i16;
        const float bv = bias[col] * bscale;
        const long row0 = m0 + wr * 64 + m * 16 + g * 4;
#pragma unroll
        for (int r = 0; r < 4; ++r)
          C[(row0 + r) * DM + col] = (__bf16)(acc[m][n][r] + bv);
      }
  }
}

__global__ __launch_bounds__(256, 3) void proj3_gemm(
    const float* __restrict__ q, const float* __restrict__ k, const float* __restrict__ v,
    const __bf16* __restrict__ wqb, const __bf16* __restrict__ wkb, const __bf16* __restrict__ wvb,
    const float* __restrict__ bq, const float* __restrict__ bk, const float* __restrict__ bv,
    __bf16* __restrict__ qpj, __bf16* __restrict__ kpj, __bf16* __restrict__ vpT) {
  const int gid = blockIdx.x;                 // 0..1151
  const int swz = (gid & 7) * 144 + (gid >> 3);
  const int z = swz / 384, rem = swz % 384;
  const long xb = rem / 6, yb = rem % 6;
  const float* A = z == 0 ? q : z == 1 ? k : v;
  const __bf16* B = z == 0 ? wqb : z == 1 ? wkb : wvb;
  const float* bias = z == 0 ? bq : z == 1 ? bk : bv;
  __bf16* C = z == 0 ? qpj : z == 1 ? kpj : vpT;
  proj_body(A, B, bias, C, xb * 128, yb * 128, z == 0 ? ALPHA : 1.0f, z == 2);
}

// ---------------- output GEMM: 64x128 tiles, 768 blocks = 3/CU exact ----------------
__global__ __launch_bounds__(256) void out_gemm(const __bf16* __restrict__ A,
                                                const __bf16* __restrict__ B,
                                                const float* __restrict__ bias,
                                                float* __restrict__ C) {
  const int gid = blockIdx.x;                 // 0..767
  const int local = (gid >> 3);               // 0..95
  const long mt = (gid & 7) * 16 + local / 6;
  const long nt = local % 6;
  const long m0 = mt * 64, n0 = nt * 128;

  __shared__ __align__(16) char LDSG[24576];
  const int tid = threadIdx.x;
  const int w = tid >> 6, l = tid & 63;
  const int g = l >> 4, i16 = l & 15;
  const int wr = w >> 1, wc = w & 1;
  const int srow = l >> 2;
  const int swc = (l & 3) ^ ((srow >> 1) & 3);
  const __bf16* Ag = A + (m0 + 16 * w + srow) * (long)DM + swc * 8;
  const __bf16* Bg = B + (n0 + 16 * w + srow) * (long)DM + swc * 8;
  const int chsw = (g ^ ((i16 >> 1) & 3)) * 16;
  const char* fA = LDSG + (wr * 32 + i16) * 64 + chsw;
  const char* fB = LDSG + 8192 + (wc * 64 + i16) * 64 + chsw;

  f32x4 acc[2][4] = {};
  long kB = 0;

#define GSTAGE(S) do { \
    gload16(Ag + kB, LDSG + (S) * 4096 + w * 1024); \
    gload16(Bg + kB, LDSG + 8192 + (S) * 8192 + w * 1024); \
    gload16(Bg + 64 * (long)DM + kB, LDSG + 8192 + (S) * 8192 + w * 1024 + 4096); \
    kB += 32; } while (0)

#define GCOMPUTE(S) do { \
    bf16x8 af[2], bfr[4]; \
    _Pragma("unroll") for (int m = 0; m < 2; ++m) \
      af[m] = *(const bf16x8*)(fA + (S) * 4096 + m * 1024); \
    _Pragma("unroll") for (int n = 0; n < 4; ++n) \
      bfr[n] = *(const bf16x8*)(fB + (S) * 8192 + n * 1024); \
    __builtin_amdgcn_s_setprio(1); \
    _Pragma("unroll") for (int m = 0; m < 2; ++m) \
      _Pragma("unroll") for (int n = 0; n < 4; ++n) \
        acc[m][n] = mfma16(af[m], bfr[n], acc[m][n]); \
    __builtin_amdgcn_s_setprio(0); } while (0)

  GSTAGE(0); GSTAGE(1);
#pragma unroll 1
  for (int k = 0; k + 128 <= DM; k += 64) {
    VMW(3); BARX; GCOMPUTE(0); BARX; GSTAGE(0);
    VMW(3); BARX; GCOMPUTE(1); BARX; GSTAGE(1);
  }
  VMW(3); BARX; GCOMPUTE(0);
  VMW(0); BARX; GCOMPUTE(1);
#undef GSTAGE
#undef GCOMPUTE

#pragma unroll
  for (int m = 0; m < 2; ++m)
#pragma unroll
    for (int n = 0; n < 4; ++n) {
      const long col = n0 + wc * 64 + n * 16 + i16;
      const float bv = bias[col];
      const long row0 = m0 + wr * 32 + m * 16 + g * 4;
#pragma unroll
      for (int r = 0; r < 4; ++r)
        C[(row0 + r) * DM + col] = acc[m][n][r] + bv;
    }
}

// ---------------- flash attention: PV pipeline + mfma-lsum + literal offsets ----------------
// grid 768 (XCD-bijective: 6 bh per XCD), 4 waves x 32 q-rows, 64-key tiles,
// double-buffered gload_lds staging, one __syncthreads per tile.
// PV deferred one tile (vfp/pfp regs). lsum on the MATRIX pipe:
// lacc = mfma32(ones, pfp) -> each column q of D = sum over ALL 16 keys of the
// k-step (rows identical, both half-lanes identical) => lacc[0] IS the full
// key-sum for query l31; epilogue uses 1/lacc[0] directly (NO pair-combine).
// LDS bytes: K0@0 K1@8192 V0@16384 V1@24576.
__global__ __launch_bounds__(256, 3) void attn_fwd(const __bf16* __restrict__ qp,
                                                   const __bf16* __restrict__ kp,
                                                   const __bf16* __restrict__ vpT,
                                                   __bf16* __restrict__ ao) {
  __shared__ __align__(16) char KV[32768];

  const int wg = blockIdx.x;          // 0..767
  const int xcd = wg & 7;
  const int idx = wg >> 3;            // 0..95
  const int bh = xcd * 6 + (idx >> 4);
  const int qt = idx & 15;
  const int b = bh / NH, h = bh % NH;

  const int tid = threadIdx.x;
  const int w = tid >> 6, l = tid & 63;
  const int l31 = l & 31, hi = l >> 5;

  const long qrow = (long)b * SEQ + qt * 128 + w * 32 + l31;
  const __bf16* qb = qp + qrow * DM + h * HD;
  bf16x8 qf[4];
#pragma unroll
  for (int kk = 0; kk < 4; ++kk) qf[kk] = *(const bf16x8*)(qb + kk * 16 + hi * 8);

  bf16x8 onesf;
#pragma unroll
  for (int j = 0; j < 8; ++j) onesf[j] = (__bf16)1.0f;

  f32x16 o0 = {}, o1 = {}, lacc = {};
  bf16x8 vfp[8], pfp[4];   // deferred-PV state (tile t-1)

  // per-lane LDS byte offsets (precomputed; buffer/V/row-block are immediates)
  int vadd[4];
#pragma unroll
  for (int kk = 0; kk < 4; ++kk)
    vadd[kk] = l31 * 128 + (((kk * 2 + hi) ^ (l31 & 7)) * 16);
  const char* kvb = KV;

  const int srow = tid >> 3;                       // 0..31
  const int schunk = (tid & 7) ^ (srow & 7);
  const __bf16* kg = kp + ((long)b * SEQ + srow) * DM + h * HD + schunk * 8;
  const __bf16* vg = vpT + ((long)(h * HD) + srow) * M8 + (long)b * SEQ + schunk * 8;
  char* const kdst = KV + w * 1024;

#define ASTAGE(SELB) do { \
    gload16(kg, kdst + (SELB)); \
    gload16(kg + 32 * (long)DM, kdst + (SELB) + 4096); \
    gload16(vg, kdst + 16384 + (SELB)); \
    gload16(vg + 32 * (long)M8, kdst + 16384 + (SELB) + 4096); \
    kg += 64 * (long)DM; vg += 64; } while (0)

#define ABODY(SELB, DOPV) do { \
    bf16x8 kf[8]; \
    _Pragma("unroll") for (int kk = 0; kk < 4; ++kk) { \
      kf[kk]     = *(const bf16x8*)(kvb + vadd[kk] + (SELB)); \
      kf[4 + kk] = *(const bf16x8*)(kvb + vadd[kk] + (SELB) + 4096); \
    } \
    f32x16 s0 = {}, s1 = {}; \
    __builtin_amdgcn_s_setprio(1); \
    if (DOPV) { \
      _Pragma("unroll") for (int ks = 0; ks < 4; ++ks) { \
        o0 = mfma32(vfp[ks], pfp[ks], o0); \
        o1 = mfma32(vfp[4 + ks], pfp[ks], o1); \
        lacc = mfma32(onesf, pfp[ks], lacc); \
      } \
    } \
    _Pragma("unroll") for (int kk = 0; kk < 4; ++kk) { \
      s0 = mfma32(kf[kk], qf[kk], s0); \
      s1 = mfma32(kf[4 + kk], qf[kk], s1); \
    } \
    __builtin_amdgcn_s_setprio(0); \
    _Pragma("unroll") for (int ks = 0; ks < 4; ++ks) { \
      vfp[ks]     = *(const bf16x8*)(kvb + vadd[ks] + 16384 + (SELB)); \
      vfp[4 + ks] = *(const bf16x8*)(kvb + vadd[ks] + 16384 + (SELB) + 4096); \
    } \
    _Pragma("unroll") for (int r = 0; r < 16; ++r) s0[r] = exp2_(s0[r]); \
    _Pragma("unroll") for (int r = 0; r < 16; ++r) s1[r] = exp2_(s1[r]); \
    _Pragma("unroll") for (int ks = 0; ks < 4; ++ks) { \
      const int base = 8 * (ks & 1); \
      const f32x16& S = (ks < 2) ? s0 : s1; \
      unsigned pa = pk(S[base + 0], S[base + 1]); \
      unsigned pc = pk(S[base + 2], S[base + 3]); \
      unsigned pb = pk(S[base + 4], S[base + 5]); \
      unsigned pd = pk(S[base + 6], S[base + 7]); \
      u32x2 r02 = pswap(pa, pb); \
      u32x2 r13 = pswap(pc, pd); \
      u32x4 pw; \
      pw[0] = r02[0]; pw[1] = r13[0]; pw[2] = r02[1]; pw[3] = r13[1]; \
      pfp[ks] = __builtin_bit_cast(bf16x8, pw); \
    } \
  } while (0)

  ASTAGE(0);      // tile 0 -> buf0
  ASTAGE(8192);   // tile 1 -> buf1
  __syncthreads();
  ABODY(0, false);            // tile 0 (QK only)
  __syncthreads();
#pragma unroll 1
  for (int t = 1; t + 1 < SEQ / 64; t += 2) {
    if (t + 1 < SEQ / 64) ASTAGE(0);      // tile t+1 -> buf0 (consumed: tile t-1)
    ABODY(8192, true);                    // tile t (buf1) + PV(t-1)
    __syncthreads();
    if (t + 2 < SEQ / 64) ASTAGE(8192);   // tile t+2 -> buf1
    ABODY(0, true);                       // tile t+1 (buf0) + PV(t)
    __syncthreads();
  }
  ABODY(8192, true);          // tile 31 (buf1) + PV(30)
  {  // drain: PV + lsum for tile 31
    __builtin_amdgcn_s_setprio(1);
#pragma unroll
    for (int ks = 0; ks < 4; ++ks) {
      o0 = mfma32(vfp[ks], pfp[ks], o0);
      o1 = mfma32(vfp[4 + ks], pfp[ks], o1);
      lacc = mfma32(onesf, pfp[ks], lacc);
    }
    __builtin_amdgcn_s_setprio(0);
  }
#undef ASTAGE
#undef ABODY

  const float inv = 1.0f / lacc[0];   // full key-sum already (no pair-combine)
  __bf16* obase = ao + qrow * DM + h * HD;
#pragma unroll
  for (int rg = 0; rg < 4; ++rg) {
    bf16x4 v0, v1;
#pragma unroll
    for (int j = 0; j < 4; ++j) {
      v0[j] = (__bf16)(o0[rg * 4 + j] * inv);
      v1[j] = (__bf16)(o1[rg * 4 + j] * inv);
    }
    *(bf16x4*)(obase + 8 * rg + 4 * hi) = v0;
    *(bf16x4*)(obase + 32 + 8 * rg + 4 * hi) = v1;
  }
}

// ---------------- launch ----------------
extern "C" void kernel_launch(void* const* d_in, const int* in_sizes, int n_in,
                              void* d_out, int out_size, void* d_ws, size_t ws_size,
                              hipStream_t stream) {
  const float* q  = (const float*)d_in[0];
  const float* k  = (const float*)d_in[1];
  const float* v  = (const float*)d_in[2];
  const float* wq = (const float*)d_in[3];
  const float* bq = (const float*)d_in[4];
  const float* wk = (const float*)d_in[5];
  const float* bk = (const float*)d_in[6];
  const float* wv = (const float*)d_in[7];
  const float* bv = (const float*)d_in[8];
  const float* wo = (const float*)d_in[9];
  const float* bo = (const float*)d_in[10];

  const long S = (long)M8 * DM;   // 6291456
  const long W = (long)DM * DM;   // 589824
  __bf16* ws = (__bf16*)d_ws;
  __bf16 *wqb = ws, *wkb = wqb + W, *wvb = wkb + W, *wob = wvb + W;
  __bf16 *qpj = wob + W, *kpj = qpj + S, *vpT = kpj + S, *aob = vpT + S;

  cast4_kernel<<<dim3((unsigned)(W / 4 / 256), 4), 256, 0, stream>>>(
      wq, wk, wv, wo, wqb, wkb, wvb, wob, (int)(W / 4));

  proj3_gemm<<<1152, 256, 0, stream>>>(q, k, v, wqb, wkb, wvb, bq, bk, bv, qpj, kpj, vpT);

  attn_fwd<<<768, 256, 0, stream>>>(qpj, kpj, vpT, aob);

  out_gemm<<<768, 256, 0, stream>>>(aob, wob, bo, (float*)d_out);
}

// Round 12
// 155.938 us; speedup vs baseline: 1.3543x; 1.3543x over previous
//
#include <hip/hip_runtime.h>
#include <hip/hip_bf16.h>
#include <type_traits>

// MultiHeadAttention fwd, MI355X/gfx950.
// Pipeline (bf16 MFMA, fp32 accum):
//   1. cast weights fp32->bf16 (wq scaled by ALPHA = 0.125*log2e)
//   2. merged projection GEMM: A staged as fp32 via global_load_lds (all-DMA,
//      counted vmcnt(6), cvt-on-read), B bf16 DMA: qp, kp, vpT
//   3. flash attention: r9 structure (typed __shared__ arrays - generic-pointer
//      LDS access in r11 compiled to flat loads, 2x regression) + cross-tile PV
//      pipeline + mfma-lsum (lacc[0] is the FULL key-sum -> inv=1/lacc[0])
//   4. out = ao@wo^T+bo (fp32), 64x128-tile counted-vmcnt GEMM, 768 blocks

typedef __attribute__((ext_vector_type(8)))  __bf16 bf16x8;
typedef __attribute__((ext_vector_type(4)))  __bf16 bf16x4;
typedef __attribute__((ext_vector_type(4)))  float  f32x4;
typedef __attribute__((ext_vector_type(16))) float  f32x16;
typedef __attribute__((ext_vector_type(2)))  unsigned u32x2;
typedef __attribute__((ext_vector_type(4)))  unsigned u32x4;

#define NH  12
#define HD  64
#define DM  768
#define SEQ 2048
#define NB  4
#define M8  8192   // NB*SEQ
#define ALPHA 0.18033688011112043f  // 0.125 * log2(e): softmax scale in exp2 domain

__device__ __forceinline__ f32x4 mfma16(bf16x8 a, bf16x8 b, f32x4 c) {
  return __builtin_amdgcn_mfma_f32_16x16x32_bf16(a, b, c, 0, 0, 0);
}
__device__ __forceinline__ f32x16 mfma32(bf16x8 a, bf16x8 b, f32x16 c) {
  return __builtin_amdgcn_mfma_f32_32x32x16_bf16(a, b, c, 0, 0, 0);
}
__device__ __forceinline__ void gload16(const void* g, void* l) {
  auto gp = (__attribute__((address_space(1))) void*)(const_cast<void*>(g));
  auto lp = (__attribute__((address_space(3))) void*)(l);
  __builtin_amdgcn_global_load_lds(gp, lp, 16, 0, 0);
}
// raw v_exp_f32 (2^x). OCML exp2f's denorm path cost ~24us (rounds 4/5).
__device__ __forceinline__ float exp2_(float x) {
#if __has_builtin(__builtin_amdgcn_exp2f)
  return __builtin_amdgcn_exp2f(x);
#else
  return exp2f(x);
#endif
}

// counted waits + raw barrier
#define VMW(n) do { asm volatile("s_waitcnt vmcnt(" #n ")" ::: "memory"); \
                    __builtin_amdgcn_sched_barrier(0); } while (0)
#define BARX do { __builtin_amdgcn_s_barrier(); \
                  __builtin_amdgcn_sched_barrier(0); } while (0)

// lane-pair (l <-> l^32) half swap. r[0]=new_vdst, r[1]=new_vsrc.
__device__ __forceinline__ u32x2 pswap(unsigned a, unsigned b) {
#if __has_builtin(__builtin_amdgcn_permlane32_swap)
  return __builtin_amdgcn_permlane32_swap(a, b, false, false);
#else
  u32x2 r;
  unsigned sa = (unsigned)__shfl_xor((int)a, 32), sb = (unsigned)__shfl_xor((int)b, 32);
  int hi = ((int)threadIdx.x >> 5) & 1;
  r[0] = hi ? sb : a;
  r[1] = hi ? b : sa;
  return r;
#endif
}
// pack two f32 -> one u32 of 2 bf16 (lo in low half); compiler fuses to cvt_pk.
__device__ __forceinline__ unsigned pk(float lo, float hi_) {
  unsigned short ua = __builtin_bit_cast(unsigned short, (__bf16)lo);
  unsigned short ub = __builtin_bit_cast(unsigned short, (__bf16)hi_);
  return ((unsigned)ub << 16) | ua;
}

// ---------------- weight cast (wq pre-scaled by ALPHA) ----------------
__global__ void cast4_kernel(const float* __restrict__ a, const float* __restrict__ b,
                             const float* __restrict__ c, const float* __restrict__ d,
                             __bf16* __restrict__ oa, __bf16* __restrict__ ob,
                             __bf16* __restrict__ oc, __bf16* __restrict__ od, int n4) {
  int y = blockIdx.y;
  const float* in = y == 0 ? a : y == 1 ? b : y == 2 ? c : d;
  __bf16* out     = y == 0 ? oa : y == 1 ? ob : y == 2 ? oc : od;
  const float sc  = y == 0 ? ALPHA : 1.0f;
  int i = blockIdx.x * 256 + threadIdx.x;
  if (i < n4) {
    float4 v = ((const float4*)in)[i];
    bf16x4 r;
    r[0] = (__bf16)(v.x * sc); r[1] = (__bf16)(v.y * sc);
    r[2] = (__bf16)(v.z * sc); r[3] = (__bf16)(v.w * sc);
    ((bf16x4*)out)[i] = r;
  }
}

// ---------------- projection GEMM: C = A_f32[M8,DM] * B[DM,DM]^T + bscale*bias ----
// All-DMA staging: A fp32 via gload_lds (16KB/step, source XOR-swizzled per 16B
// chunk: c ^= row&7), B bf16 via gload_lds (8KB/step).
// A frags: 2 swizzled ds_read_b128 (fp32) + 4 cvt_pk per m -> bf16x8.
// LDS (bytes): A0@0 A1@16384 B0@32768 B1@40960  (48KB, 3 blocks/CU).
// Counted vmcnt(6) (6 DMA/step/wave), two-barrier K-loop, no drain in loop.
__device__ __forceinline__ void proj_body(const float* __restrict__ A,
                                          const __bf16* __restrict__ B,
                                          const float* __restrict__ bias,
                                          __bf16* __restrict__ C,
                                          long m0, long n0, float bscale, bool trans) {
  __shared__ __align__(16) char LDSG[49152];
  const int tid = threadIdx.x;
  const int w = tid >> 6, l = tid & 63;
  const int g = l >> 4, i16 = l & 15;
  const int wr = w >> 1, wc = w & 1;

  // A staging: lane covers row w*8 + (l>>3) (+j*32), 16B chunk l&7; src pre-swizzled
  const int schA = (l & 7) ^ ((l >> 3) & 7);
  const float* Ag = A + (m0 + w * 8 + (l >> 3)) * (long)DM + schA * 4;
  // B staging (proven scheme)
  const int srowB = l >> 2;
  const int swcB = (l & 3) ^ ((srowB >> 1) & 3);
  const __bf16* Bg = B + (n0 + 16 * w + srowB) * (long)DM + swcB * 8;

  // A frag read ptrs: row R = wr*64 + m*16 + i16 (R&7 == i16&7), chunk (2g)^rsw
  const int rsw = i16 & 7;
  const char* pA0 = LDSG + (wr * 64 + i16) * 128 + (((2 * g) ^ rsw) * 16);
  const char* pA1 = LDSG + (wr * 64 + i16) * 128 + ((((2 * g) ^ rsw) ^ 1) * 16);
  // B frag ptr
  const char* fB = LDSG + 32768 + (wc * 64 + i16) * 64 + (g ^ ((i16 >> 1) & 3)) * 16;

  f32x4 acc[4][4] = {};
  long kk0 = 0;

#define PSTAGE(SA, SB2) do { \
    _Pragma("unroll") for (int j = 0; j < 4; ++j) \
      gload16(Ag + (long)j * 32 * DM + kk0, LDSG + (SA) + (j * 32 + w * 8) * 128); \
    gload16(Bg + kk0, LDSG + 32768 + (SB2) + w * 1024); \
    gload16(Bg + 64 * (long)DM + kk0, LDSG + 32768 + (SB2) + w * 1024 + 4096); \
    kk0 += 32; } while (0)

#define PCOMP(SA, SB2) do { \
    bf16x8 af[4], bfr[4]; \
    _Pragma("unroll") for (int m = 0; m < 4; ++m) { \
      f32x4 lo = *(const f32x4*)(pA0 + (SA) + m * 2048); \
      f32x4 hh = *(const f32x4*)(pA1 + (SA) + m * 2048); \
      u32x4 u; \
      u[0] = pk(lo[0], lo[1]); u[1] = pk(lo[2], lo[3]); \
      u[2] = pk(hh[0], hh[1]); u[3] = pk(hh[2], hh[3]); \
      af[m] = __builtin_bit_cast(bf16x8, u); \
    } \
    _Pragma("unroll") for (int n = 0; n < 4; ++n) \
      bfr[n] = *(const bf16x8*)(fB + (SB2) + n * 1024); \
    __builtin_amdgcn_s_setprio(1); \
    _Pragma("unroll") for (int m = 0; m < 4; ++m) \
      _Pragma("unroll") for (int n = 0; n < 4; ++n) \
        acc[m][n] = mfma16(af[m], bfr[n], acc[m][n]); \
    __builtin_amdgcn_s_setprio(0); } while (0)

  PSTAGE(0, 0); PSTAGE(16384, 8192);
#pragma unroll 1
  for (int j2 = 0; j2 < 11; ++j2) {
    VMW(6); BARX; PCOMP(0, 0);         BARX; PSTAGE(0, 0);
    VMW(6); BARX; PCOMP(16384, 8192);  BARX; PSTAGE(16384, 8192);
  }
  VMW(6); BARX; PCOMP(0, 0);          // step 22
  VMW(0); BARX; PCOMP(16384, 8192);   // step 23
#undef PSTAGE
#undef PCOMP

  if (trans) {
#pragma unroll
    for (int m = 0; m < 4; ++m)
#pragma unroll
      for (int n = 0; n < 4; ++n) {
        const long col = n0 + wc * 64 + n * 16 + i16;
        const float bv = bias[col] * bscale;
        const long row0 = m0 + wr * 64 + m * 16 + g * 4;
        bf16x4 v4;
#pragma unroll
        for (int r = 0; r < 4; ++r) v4[r] = (__bf16)(acc[m][n][r] + bv);
        *(bf16x4*)(C + col * (long)M8 + row0) = v4;
      }
  } else {
#pragma unroll
    for (int m = 0; m < 4; ++m)
#pragma unroll
      for (int n = 0; n < 4; ++n) {
        const long col = n0 + wc * 64 + n * 16 + i16;
        const float bv = bias[col] * bscale;
        const long row0 = m0 + wr * 64 + m * 16 + g * 4;
#pragma unroll
        for (int r = 0; r < 4; ++r)
          C[(row0 + r) * DM + col] = (__bf16)(acc[m][n][r] + bv);
      }
  }
}

__global__ __launch_bounds__(256, 3) void proj3_gemm(
    const float* __restrict__ q, const float* __restrict__ k, const float* __restrict__ v,
    const __bf16* __restrict__ wqb, const __bf16* __restrict__ wkb, const __bf16* __restrict__ wvb,
    const float* __restrict__ bq, const float* __restrict__ bk, const float* __restrict__ bv,
    __bf16* __restrict__ qpj, __bf16* __restrict__ kpj, __bf16* __restrict__ vpT) {
  const int gid = blockIdx.x;                 // 0..1151
  const int swz = (gid & 7) * 144 + (gid >> 3);
  const int z = swz / 384, rem = swz % 384;
  const long xb = rem / 6, yb = rem % 6;
  const float* A = z == 0 ? q : z == 1 ? k : v;
  const __bf16* B = z == 0 ? wqb : z == 1 ? wkb : wvb;
  const float* bias = z == 0 ? bq : z == 1 ? bk : bv;
  __bf16* C = z == 0 ? qpj : z == 1 ? kpj : vpT;
  proj_body(A, B, bias, C, xb * 128, yb * 128, z == 0 ? ALPHA : 1.0f, z == 2);
}

// ---------------- output GEMM: 64x128 tiles, 768 blocks = 3/CU exact ----------------
__global__ __launch_bounds__(256) void out_gemm(const __bf16* __restrict__ A,
                                                const __bf16* __restrict__ B,
                                                const float* __restrict__ bias,
                                                float* __restrict__ C) {
  const int gid = blockIdx.x;                 // 0..767
  const int local = (gid >> 3);               // 0..95
  const long mt = (gid & 7) * 16 + local / 6;
  const long nt = local % 6;
  const long m0 = mt * 64, n0 = nt * 128;

  __shared__ __align__(16) char LDSG[24576];
  const int tid = threadIdx.x;
  const int w = tid >> 6, l = tid & 63;
  const int g = l >> 4, i16 = l & 15;
  const int wr = w >> 1, wc = w & 1;
  const int srow = l >> 2;
  const int swc = (l & 3) ^ ((srow >> 1) & 3);
  const __bf16* Ag = A + (m0 + 16 * w + srow) * (long)DM + swc * 8;
  const __bf16* Bg = B + (n0 + 16 * w + srow) * (long)DM + swc * 8;
  const int chsw = (g ^ ((i16 >> 1) & 3)) * 16;
  const char* fA = LDSG + (wr * 32 + i16) * 64 + chsw;
  const char* fB = LDSG + 8192 + (wc * 64 + i16) * 64 + chsw;

  f32x4 acc[2][4] = {};
  long kB = 0;

#define GSTAGE(S) do { \
    gload16(Ag + kB, LDSG + (S) * 4096 + w * 1024); \
    gload16(Bg + kB, LDSG + 8192 + (S) * 8192 + w * 1024); \
    gload16(Bg + 64 * (long)DM + kB, LDSG + 8192 + (S) * 8192 + w * 1024 + 4096); \
    kB += 32; } while (0)

#define GCOMPUTE(S) do { \
    bf16x8 af[2], bfr[4]; \
    _Pragma("unroll") for (int m = 0; m < 2; ++m) \
      af[m] = *(const bf16x8*)(fA + (S) * 4096 + m * 1024); \
    _Pragma("unroll") for (int n = 0; n < 4; ++n) \
      bfr[n] = *(const bf16x8*)(fB + (S) * 8192 + n * 1024); \
    __builtin_amdgcn_s_setprio(1); \
    _Pragma("unroll") for (int m = 0; m < 2; ++m) \
      _Pragma("unroll") for (int n = 0; n < 4; ++n) \
        acc[m][n] = mfma16(af[m], bfr[n], acc[m][n]); \
    __builtin_amdgcn_s_setprio(0); } while (0)

  GSTAGE(0); GSTAGE(1);
#pragma unroll 1
  for (int k = 0; k + 128 <= DM; k += 64) {
    VMW(3); BARX; GCOMPUTE(0); BARX; GSTAGE(0);
    VMW(3); BARX; GCOMPUTE(1); BARX; GSTAGE(1);
  }
  VMW(3); BARX; GCOMPUTE(0);
  VMW(0); BARX; GCOMPUTE(1);
#undef GSTAGE
#undef GCOMPUTE

#pragma unroll
  for (int m = 0; m < 2; ++m)
#pragma unroll
    for (int n = 0; n < 4; ++n) {
      const long col = n0 + wc * 64 + n * 16 + i16;
      const float bv = bias[col];
      const long row0 = m0 + wr * 32 + m * 16 + g * 4;
#pragma unroll
      for (int r = 0; r < 4; ++r)
        C[(row0 + r) * DM + col] = acc[m][n][r] + bv;
    }
}

// ---------------- flash attention: r9 structure + mfma-lsum ----------------
// grid 768 (XCD-bijective: 6 bh per XCD), 4 waves x 32 q-rows, 64-key tiles,
// double-buffered gload_lds staging, one __syncthreads per tile.
// PV deferred one tile (vfp/pfp regs): iter t issues kf reads -> PV(t-1)
// register-only mfmas fill matrix pipe -> QK(t) -> capture vfp(t) -> exp/pack.
// lsum on the MATRIX pipe: lacc = mfma32(ones, pfp) -> every row of D is the
// full 16-key sum and both half-lanes are identical => lacc[0] is the complete
// key-sum for query l31; epilogue uses 1/lacc[0] (validated round 11).
// Typed __shared__ arrays only (char*-based LDS access compiled to flat loads).
__global__ __launch_bounds__(256, 3) void attn_fwd(const __bf16* __restrict__ qp,
                                                   const __bf16* __restrict__ kp,
                                                   const __bf16* __restrict__ vpT,
                                                   __bf16* __restrict__ ao) {
  __shared__ __align__(16) __bf16 Ks[2][64 * 64];
  __shared__ __align__(16) __bf16 Vs[2][64 * 64];

  const int wg = blockIdx.x;          // 0..767
  const int xcd = wg & 7;
  const int idx = wg >> 3;            // 0..95
  const int bh = xcd * 6 + (idx >> 4);
  const int qt = idx & 15;
  const int b = bh / NH, h = bh % NH;

  const int tid = threadIdx.x;
  const int w = tid >> 6, l = tid & 63;
  const int l31 = l & 31, hi = l >> 5;

  const long qrow = (long)b * SEQ + qt * 128 + w * 32 + l31;
  const __bf16* qb = qp + qrow * DM + h * HD;
  bf16x8 qf[4];
#pragma unroll
  for (int kk = 0; kk < 4; ++kk) qf[kk] = *(const bf16x8*)(qb + kk * 16 + hi * 8);

  bf16x8 onesf;
#pragma unroll
  for (int j = 0; j < 8; ++j) onesf[j] = (__bf16)1.0f;

  f32x16 o0 = {}, o1 = {}, lacc = {};
  bf16x8 vfp[8], pfp[4];   // deferred-PV state (tile t-1)

  const int srow = tid >> 3;                       // 0..31
  const int schunk = (tid & 7) ^ (srow & 7);
  const __bf16* kbase = kp + ((long)b * SEQ) * DM + h * HD;
  const __bf16* vtb = vpT + (long)(h * HD) * M8 + (long)b * SEQ;

  auto stage = [&](int T, int sel) {
    const long kt = (long)T * 64;
    __bf16* Kd = &Ks[sel][(w * 8) * 64];
    __bf16* Vd = &Vs[sel][(w * 8) * 64];
    gload16(kbase + (kt + srow) * (long)DM + schunk * 8, Kd);
    gload16(kbase + (kt + 32 + srow) * (long)DM + schunk * 8, Kd + 32 * 64);
    gload16(vtb + (long)srow * M8 + kt + schunk * 8, Vd);
    gload16(vtb + (long)(32 + srow) * M8 + kt + schunk * 8, Vd + 32 * 64);
  };

  auto qk = [&](const __bf16* Kc, f32x16& s0, f32x16& s1, bool pv) {
    // kf reads issue first; PV (register-only) fills matrix pipe while they land
    bf16x8 kf[8];
#pragma unroll
    for (int kk = 0; kk < 4; ++kk) {
      const int sw = ((kk * 2 + hi) ^ (l31 & 7)) * 8;
      kf[kk]     = *(const bf16x8*)&Kc[l31 * 64 + sw];
      kf[4 + kk] = *(const bf16x8*)&Kc[2048 + l31 * 64 + sw];
    }
    __builtin_amdgcn_s_setprio(1);
    if (pv) {
#pragma unroll
      for (int ks = 0; ks < 4; ++ks) {
        o0 = mfma32(vfp[ks], pfp[ks], o0);
        o1 = mfma32(vfp[4 + ks], pfp[ks], o1);
        lacc = mfma32(onesf, pfp[ks], lacc);
      }
    }
#pragma unroll
    for (int kk = 0; kk < 4; ++kk) {
      s0 = mfma32(kf[kk], qf[kk], s0);
      s1 = mfma32(kf[4 + kk], qf[kk], s1);
    }
    __builtin_amdgcn_s_setprio(0);
  };

  auto load_v = [&](const __bf16* Vc) {
#pragma unroll
    for (int ks = 0; ks < 4; ++ks) {
      const int sw = ((ks * 2 + hi) ^ (l31 & 7)) * 8;
      vfp[ks]     = *(const bf16x8*)&Vc[l31 * 64 + sw];
      vfp[4 + ks] = *(const bf16x8*)&Vc[2048 + l31 * 64 + sw];
    }
  };

  auto softmax_pack = [&](f32x16& s0, f32x16& s1) {
#pragma unroll
    for (int r = 0; r < 16; ++r) s0[r] = exp2_(s0[r]);
#pragma unroll
    for (int r = 0; r < 16; ++r) s1[r] = exp2_(s1[r]);
#pragma unroll
    for (int ks = 0; ks < 4; ++ks) {
      const int base = 8 * (ks & 1);
      const f32x16& S = (ks < 2) ? s0 : s1;
      unsigned pa = pk(S[base + 0], S[base + 1]);
      unsigned pc = pk(S[base + 2], S[base + 3]);
      unsigned pb = pk(S[base + 4], S[base + 5]);
      unsigned pd = pk(S[base + 6], S[base + 7]);
      u32x2 r02 = pswap(pa, pb);
      u32x2 r13 = pswap(pc, pd);
      u32x4 pw;
      pw[0] = r02[0]; pw[1] = r13[0]; pw[2] = r02[1]; pw[3] = r13[1];
      pfp[ks] = __builtin_bit_cast(bf16x8, pw);
    }
  };

  stage(0, 0);
  stage(1, 1);
  __syncthreads();
  {  // iter 0: QK only (no PV yet); tiles 0,1 already resident
    f32x16 s0 = {}, s1 = {};
    qk(&Ks[0][0], s0, s1, false);
    load_v(&Vs[0][0]);
    softmax_pack(s0, s1);
    __syncthreads();   // all waves done with buffer 0 reads
  }
#pragma unroll 1
  for (int t = 1; t < SEQ / 64; ++t) {
    const int sel = t & 1;
    if (t + 1 < SEQ / 64) stage(t + 1, sel ^ 1);  // buffer sel^1 fully consumed
    f32x16 s0 = {}, s1 = {};
    qk(&Ks[sel][0], s0, s1, true);                // PV(t-1) + QK(t)
    load_v(&Vs[sel][0]);
    softmax_pack(s0, s1);
    __syncthreads();   // drains own DMAs + buffer handoff
  }
  {  // epilogue PV + lsum for last tile
    __builtin_amdgcn_s_setprio(1);
#pragma unroll
    for (int ks = 0; ks < 4; ++ks) {
      o0 = mfma32(vfp[ks], pfp[ks], o0);
      o1 = mfma32(vfp[4 + ks], pfp[ks], o1);
      lacc = mfma32(onesf, pfp[ks], lacc);
    }
    __builtin_amdgcn_s_setprio(0);
  }

  const float inv = 1.0f / lacc[0];   // full key-sum already (no pair-combine)
  __bf16* obase = ao + qrow * DM + h * HD;
#pragma unroll
  for (int rg = 0; rg < 4; ++rg) {
    bf16x4 v0, v1;
#pragma unroll
    for (int j = 0; j < 4; ++j) {
      v0[j] = (__bf16)(o0[rg * 4 + j] * inv);
      v1[j] = (__bf16)(o1[rg * 4 + j] * inv);
    }
    *(bf16x4*)(obase + 8 * rg + 4 * hi) = v0;
    *(bf16x4*)(obase + 32 + 8 * rg + 4 * hi) = v1;
  }
}

// ---------------- launch ----------------
extern "C" void kernel_launch(void* const* d_in, const int* in_sizes, int n_in,
                              void* d_out, int out_size, void* d_ws, size_t ws_size,
                              hipStream_t stream) {
  const float* q  = (const float*)d_in[0];
  const float* k  = (const float*)d_in[1];
  const float* v  = (const float*)d_in[2];
  const float* wq = (const float*)d_in[3];
  const float* bq = (const float*)d_in[4];
  const float* wk = (const float*)d_in[5];
  const float* bk = (const float*)d_in[6];
  const float* wv = (const float*)d_in[7];
  const float* bv = (const float*)d_in[8];
  const float* wo = (const float*)d_in[9];
  const float* bo = (const float*)d_in[10];

  const long S = (long)M8 * DM;   // 6291456
  const long W = (long)DM * DM;   // 589824
  __bf16* ws = (__bf16*)d_ws;
  __bf16 *wqb = ws, *wkb = wqb + W, *wvb = wkb + W, *wob = wvb + W;
  __bf16 *qpj = wob + W, *kpj = qpj + S, *vpT = kpj + S, *aob = vpT + S;

  cast4_kernel<<<dim3((unsigned)(W / 4 / 256), 4), 256, 0, stream>>>(
      wq, wk, wv, wo, wqb, wkb, wvb, wob, (int)(W / 4));

  proj3_gemm<<<1152, 256, 0, stream>>>(q, k, v, wqb, wkb, wvb, bq, bk, bv, qpj, kpj, vpT);

  attn_fwd<<<768, 256, 0, stream>>>(qpj, kpj, vpT, aob);

  out_gemm<<<768, 256, 0, stream>>>(aob, wob, bo, (float*)d_out);
}

// Round 13
// 151.359 us; speedup vs baseline: 1.3952x; 1.0303x over previous
//
#include <hip/hip_runtime.h>
#include <hip/hip_bf16.h>
#include <type_traits>

// MultiHeadAttention fwd, MI355X/gfx950.
// Best-of composition (r13):
//   1. cast weights fp32->bf16 (wq scaled by ALPHA = 0.125*log2e)
//   2. merged projection GEMM: A staged as fp32 via global_load_lds (all-DMA,
//      counted vmcnt(6), cvt-on-read), B bf16 DMA: qp, kp, vpT    [r11]
//   3. flash attention: r9 structure exactly — typed __shared__, cross-tile PV
//      pipeline, VALU lsum tree (mfma-lsum regressed: it added matrix-pipe ops
//      on the critical path while the VALU tree overlapped deferred-PV MFMAs)
//   4. out = ao@wo^T+bo (fp32), 64x128-tile counted-vmcnt GEMM, 768 blocks [r8]

typedef __attribute__((ext_vector_type(8)))  __bf16 bf16x8;
typedef __attribute__((ext_vector_type(4)))  __bf16 bf16x4;
typedef __attribute__((ext_vector_type(4)))  float  f32x4;
typedef __attribute__((ext_vector_type(16))) float  f32x16;
typedef __attribute__((ext_vector_type(2)))  unsigned u32x2;
typedef __attribute__((ext_vector_type(4)))  unsigned u32x4;

#define NH  12
#define HD  64
#define DM  768
#define SEQ 2048
#define NB  4
#define M8  8192   // NB*SEQ
#define ALPHA 0.18033688011112043f  // 0.125 * log2(e): softmax scale in exp2 domain

__device__ __forceinline__ f32x4 mfma16(bf16x8 a, bf16x8 b, f32x4 c) {
  return __builtin_amdgcn_mfma_f32_16x16x32_bf16(a, b, c, 0, 0, 0);
}
__device__ __forceinline__ f32x16 mfma32(bf16x8 a, bf16x8 b, f32x16 c) {
  return __builtin_amdgcn_mfma_f32_32x32x16_bf16(a, b, c, 0, 0, 0);
}
__device__ __forceinline__ void gload16(const void* g, void* l) {
  auto gp = (__attribute__((address_space(1))) void*)(const_cast<void*>(g));
  auto lp = (__attribute__((address_space(3))) void*)(l);
  __builtin_amdgcn_global_load_lds(gp, lp, 16, 0, 0);
}
// raw v_exp_f32 (2^x). OCML exp2f's denorm path cost ~24us (rounds 4/5).
__device__ __forceinline__ float exp2_(float x) {
#if __has_builtin(__builtin_amdgcn_exp2f)
  return __builtin_amdgcn_exp2f(x);
#else
  return exp2f(x);
#endif
}

// counted waits + raw barrier
#define VMW(n) do { asm volatile("s_waitcnt vmcnt(" #n ")" ::: "memory"); \
                    __builtin_amdgcn_sched_barrier(0); } while (0)
#define BARX do { __builtin_amdgcn_s_barrier(); \
                  __builtin_amdgcn_sched_barrier(0); } while (0)

// lane-pair (l <-> l^32) half swap. r[0]=new_vdst, r[1]=new_vsrc.
__device__ __forceinline__ u32x2 pswap(unsigned a, unsigned b) {
#if __has_builtin(__builtin_amdgcn_permlane32_swap)
  return __builtin_amdgcn_permlane32_swap(a, b, false, false);
#else
  u32x2 r;
  unsigned sa = (unsigned)__shfl_xor((int)a, 32), sb = (unsigned)__shfl_xor((int)b, 32);
  int hi = ((int)threadIdx.x >> 5) & 1;
  r[0] = hi ? sb : a;
  r[1] = hi ? b : sa;
  return r;
#endif
}
__device__ __forceinline__ unsigned f2u(float x) { return __builtin_bit_cast(unsigned, x); }
__device__ __forceinline__ float    u2f(unsigned x) { return __builtin_bit_cast(float, x); }
__device__ __forceinline__ float pcomb_sum(float v) {
  u32x2 r = pswap(f2u(v), f2u(v));
  return u2f(r[0]) + u2f(r[1]);
}
// pack two f32 -> one u32 of 2 bf16 (lo in low half); compiler fuses to cvt_pk.
__device__ __forceinline__ unsigned pk(float lo, float hi_) {
  unsigned short ua = __builtin_bit_cast(unsigned short, (__bf16)lo);
  unsigned short ub = __builtin_bit_cast(unsigned short, (__bf16)hi_);
  return ((unsigned)ub << 16) | ua;
}

// ---------------- weight cast (wq pre-scaled by ALPHA) ----------------
__global__ void cast4_kernel(const float* __restrict__ a, const float* __restrict__ b,
                             const float* __restrict__ c, const float* __restrict__ d,
                             __bf16* __restrict__ oa, __bf16* __restrict__ ob,
                             __bf16* __restrict__ oc, __bf16* __restrict__ od, int n4) {
  int y = blockIdx.y;
  const float* in = y == 0 ? a : y == 1 ? b : y == 2 ? c : d;
  __bf16* out     = y == 0 ? oa : y == 1 ? ob : y == 2 ? oc : od;
  const float sc  = y == 0 ? ALPHA : 1.0f;
  int i = blockIdx.x * 256 + threadIdx.x;
  if (i < n4) {
    float4 v = ((const float4*)in)[i];
    bf16x4 r;
    r[0] = (__bf16)(v.x * sc); r[1] = (__bf16)(v.y * sc);
    r[2] = (__bf16)(v.z * sc); r[3] = (__bf16)(v.w * sc);
    ((bf16x4*)out)[i] = r;
  }
}

// ---------------- projection GEMM: C = A_f32[M8,DM] * B[DM,DM]^T + bscale*bias ----
// All-DMA staging: A fp32 via gload_lds (16KB/step, source XOR-swizzled per 16B
// chunk: c ^= row&7), B bf16 via gload_lds (8KB/step).
// A frags: 2 swizzled ds_read_b128 (fp32) + 4 cvt_pk per m -> bf16x8.
// LDS (bytes): A0@0 A1@16384 B0@32768 B1@40960  (48KB, 3 blocks/CU).
// Counted vmcnt(6) (6 DMA/step/wave), two-barrier K-loop, no drain in loop.
__device__ __forceinline__ void proj_body(const float* __restrict__ A,
                                          const __bf16* __restrict__ B,
                                          const float* __restrict__ bias,
                                          __bf16* __restrict__ C,
                                          long m0, long n0, float bscale, bool trans) {
  __shared__ __align__(16) char LDSG[49152];
  const int tid = threadIdx.x;
  const int w = tid >> 6, l = tid & 63;
  const int g = l >> 4, i16 = l & 15;
  const int wr = w >> 1, wc = w & 1;

  // A staging: lane covers row w*8 + (l>>3) (+j*32), 16B chunk l&7; src pre-swizzled
  const int schA = (l & 7) ^ ((l >> 3) & 7);
  const float* Ag = A + (m0 + w * 8 + (l >> 3)) * (long)DM + schA * 4;
  // B staging (proven scheme)
  const int srowB = l >> 2;
  const int swcB = (l & 3) ^ ((srowB >> 1) & 3);
  const __bf16* Bg = B + (n0 + 16 * w + srowB) * (long)DM + swcB * 8;

  // A frag read ptrs: row R = wr*64 + m*16 + i16 (R&7 == i16&7), chunk (2g)^rsw
  const int rsw = i16 & 7;
  const char* pA0 = LDSG + (wr * 64 + i16) * 128 + (((2 * g) ^ rsw) * 16);
  const char* pA1 = LDSG + (wr * 64 + i16) * 128 + ((((2 * g) ^ rsw) ^ 1) * 16);
  // B frag ptr
  const char* fB = LDSG + 32768 + (wc * 64 + i16) * 64 + (g ^ ((i16 >> 1) & 3)) * 16;

  f32x4 acc[4][4] = {};
  long kk0 = 0;

#define PSTAGE(SA, SB2) do { \
    _Pragma("unroll") for (int j = 0; j < 4; ++j) \
      gload16(Ag + (long)j * 32 * DM + kk0, LDSG + (SA) + (j * 32 + w * 8) * 128); \
    gload16(Bg + kk0, LDSG + 32768 + (SB2) + w * 1024); \
    gload16(Bg + 64 * (long)DM + kk0, LDSG + 32768 + (SB2) + w * 1024 + 4096); \
    kk0 += 32; } while (0)

#define PCOMP(SA, SB2) do { \
    bf16x8 af[4], bfr[4]; \
    _Pragma("unroll") for (int m = 0; m < 4; ++m) { \
      f32x4 lo = *(const f32x4*)(pA0 + (SA) + m * 2048); \
      f32x4 hh = *(const f32x4*)(pA1 + (SA) + m * 2048); \
      u32x4 u; \
      u[0] = pk(lo[0], lo[1]); u[1] = pk(lo[2], lo[3]); \
      u[2] = pk(hh[0], hh[1]); u[3] = pk(hh[2], hh[3]); \
      af[m] = __builtin_bit_cast(bf16x8, u); \
    } \
    _Pragma("unroll") for (int n = 0; n < 4; ++n) \
      bfr[n] = *(const bf16x8*)(fB + (SB2) + n * 1024); \
    __builtin_amdgcn_s_setprio(1); \
    _Pragma("unroll") for (int m = 0; m < 4; ++m) \
      _Pragma("unroll") for (int n = 0; n < 4; ++n) \
        acc[m][n] = mfma16(af[m], bfr[n], acc[m][n]); \
    __builtin_amdgcn_s_setprio(0); } while (0)

  PSTAGE(0, 0); PSTAGE(16384, 8192);
#pragma unroll 1
  for (int j2 = 0; j2 < 11; ++j2) {
    VMW(6); BARX; PCOMP(0, 0);         BARX; PSTAGE(0, 0);
    VMW(6); BARX; PCOMP(16384, 8192);  BARX; PSTAGE(16384, 8192);
  }
  VMW(6); BARX; PCOMP(0, 0);          // step 22
  VMW(0); BARX; PCOMP(16384, 8192);   // step 23
#undef PSTAGE
#undef PCOMP

  if (trans) {
#pragma unroll
    for (int m = 0; m < 4; ++m)
#pragma unroll
      for (int n = 0; n < 4; ++n) {
        const long col = n0 + wc * 64 + n * 16 + i16;
        const float bv = bias[col] * bscale;
        const long row0 = m0 + wr * 64 + m * 16 + g * 4;
        bf16x4 v4;
#pragma unroll
        for (int r = 0; r < 4; ++r) v4[r] = (__bf16)(acc[m][n][r] + bv);
        *(bf16x4*)(C + col * (long)M8 + row0) = v4;
      }
  } else {
#pragma unroll
    for (int m = 0; m < 4; ++m)
#pragma unroll
      for (int n = 0; n < 4; ++n) {
        const long col = n0 + wc * 64 + n * 16 + i16;
        const float bv = bias[col] * bscale;
        const long row0 = m0 + wr * 64 + m * 16 + g * 4;
#pragma unroll
        for (int r = 0; r < 4; ++r)
          C[(row0 + r) * DM + col] = (__bf16)(acc[m][n][r] + bv);
      }
  }
}

__global__ __launch_bounds__(256, 3) void proj3_gemm(
    const float* __restrict__ q, const float* __restrict__ k, const float* __restrict__ v,
    const __bf16* __restrict__ wqb, const __bf16* __restrict__ wkb, const __bf16* __restrict__ wvb,
    const float* __restrict__ bq, const float* __restrict__ bk, const float* __restrict__ bv,
    __bf16* __restrict__ qpj, __bf16* __restrict__ kpj, __bf16* __restrict__ vpT) {
  const int gid = blockIdx.x;                 // 0..1151
  const int swz = (gid & 7) * 144 + (gid >> 3);
  const int z = swz / 384, rem = swz % 384;
  const long xb = rem / 6, yb = rem % 6;
  const float* A = z == 0 ? q : z == 1 ? k : v;
  const __bf16* B = z == 0 ? wqb : z == 1 ? wkb : wvb;
  const float* bias = z == 0 ? bq : z == 1 ? bk : bv;
  __bf16* C = z == 0 ? qpj : z == 1 ? kpj : vpT;
  proj_body(A, B, bias, C, xb * 128, yb * 128, z == 0 ? ALPHA : 1.0f, z == 2);
}

// ---------------- output GEMM: 64x128 tiles, 768 blocks = 3/CU exact ----------------
__global__ __launch_bounds__(256) void out_gemm(const __bf16* __restrict__ A,
                                                const __bf16* __restrict__ B,
                                                const float* __restrict__ bias,
                                                float* __restrict__ C) {
  const int gid = blockIdx.x;                 // 0..767
  const int local = (gid >> 3);               // 0..95
  const long mt = (gid & 7) * 16 + local / 6;
  const long nt = local % 6;
  const long m0 = mt * 64, n0 = nt * 128;

  __shared__ __align__(16) char LDSG[24576];
  const int tid = threadIdx.x;
  const int w = tid >> 6, l = tid & 63;
  const int g = l >> 4, i16 = l & 15;
  const int wr = w >> 1, wc = w & 1;
  const int srow = l >> 2;
  const int swc = (l & 3) ^ ((srow >> 1) & 3);
  const __bf16* Ag = A + (m0 + 16 * w + srow) * (long)DM + swc * 8;
  const __bf16* Bg = B + (n0 + 16 * w + srow) * (long)DM + swc * 8;
  const int chsw = (g ^ ((i16 >> 1) & 3)) * 16;
  const char* fA = LDSG + (wr * 32 + i16) * 64 + chsw;
  const char* fB = LDSG + 8192 + (wc * 64 + i16) * 64 + chsw;

  f32x4 acc[2][4] = {};
  long kB = 0;

#define GSTAGE(S) do { \
    gload16(Ag + kB, LDSG + (S) * 4096 + w * 1024); \
    gload16(Bg + kB, LDSG + 8192 + (S) * 8192 + w * 1024); \
    gload16(Bg + 64 * (long)DM + kB, LDSG + 8192 + (S) * 8192 + w * 1024 + 4096); \
    kB += 32; } while (0)

#define GCOMPUTE(S) do { \
    bf16x8 af[2], bfr[4]; \
    _Pragma("unroll") for (int m = 0; m < 2; ++m) \
      af[m] = *(const bf16x8*)(fA + (S) * 4096 + m * 1024); \
    _Pragma("unroll") for (int n = 0; n < 4; ++n) \
      bfr[n] = *(const bf16x8*)(fB + (S) * 8192 + n * 1024); \
    __builtin_amdgcn_s_setprio(1); \
    _Pragma("unroll") for (int m = 0; m < 2; ++m) \
      _Pragma("unroll") for (int n = 0; n < 4; ++n) \
        acc[m][n] = mfma16(af[m], bfr[n], acc[m][n]); \
    __builtin_amdgcn_s_setprio(0); } while (0)

  GSTAGE(0); GSTAGE(1);
#pragma unroll 1
  for (int k = 0; k + 128 <= DM; k += 64) {
    VMW(3); BARX; GCOMPUTE(0); BARX; GSTAGE(0);
    VMW(3); BARX; GCOMPUTE(1); BARX; GSTAGE(1);
  }
  VMW(3); BARX; GCOMPUTE(0);
  VMW(0); BARX; GCOMPUTE(1);
#undef GSTAGE
#undef GCOMPUTE

#pragma unroll
  for (int m = 0; m < 2; ++m)
#pragma unroll
    for (int n = 0; n < 4; ++n) {
      const long col = n0 + wc * 64 + n * 16 + i16;
      const float bv = bias[col];
      const long row0 = m0 + wr * 32 + m * 16 + g * 4;
#pragma unroll
      for (int r = 0; r < 4; ++r)
        C[(row0 + r) * DM + col] = acc[m][n][r] + bv;
    }
}

// ---------------- flash attention: r9 structure verbatim (79.8us measured) ----------------
// grid 768 (XCD-bijective: 6 bh per XCD), 4 waves x 32 q-rows, 64-key tiles,
// double-buffered gload_lds staging, one __syncthreads per tile.
// PV deferred one tile (vfp/pfp regs): iter t issues kf reads -> PV(t-1)
// register-only mfmas fill matrix pipe -> QK(t) -> capture vfp(t) -> exp/pack.
// lsum: VALU tree on s0+s1 (overlaps deferred-PV MFMAs; the mfma-lsum variant
// added matrix-pipe ops on the critical path and regressed 79.8->85.9).
__global__ __launch_bounds__(256, 3) void attn_fwd(const __bf16* __restrict__ qp,
                                                   const __bf16* __restrict__ kp,
                                                   const __bf16* __restrict__ vpT,
                                                   __bf16* __restrict__ ao) {
  __shared__ __align__(16) __bf16 Ks[2][64 * 64];
  __shared__ __align__(16) __bf16 Vs[2][64 * 64];

  const int wg = blockIdx.x;          // 0..767
  const int xcd = wg & 7;
  const int idx = wg >> 3;            // 0..95
  const int bh = xcd * 6 + (idx >> 4);
  const int qt = idx & 15;
  const int b = bh / NH, h = bh % NH;

  const int tid = threadIdx.x;
  const int w = tid >> 6, l = tid & 63;
  const int l31 = l & 31, hi = l >> 5;

  const long qrow = (long)b * SEQ + qt * 128 + w * 32 + l31;
  const __bf16* qb = qp + qrow * DM + h * HD;
  bf16x8 qf[4];
#pragma unroll
  for (int kk = 0; kk < 4; ++kk) qf[kk] = *(const bf16x8*)(qb + kk * 16 + hi * 8);

  f32x16 o0 = {}, o1 = {};
  float lsum = 0.f;
  bf16x8 vfp[8], pfp[4];   // deferred-PV state (tile t-1)

  const int srow = tid >> 3;                       // 0..31
  const int schunk = (tid & 7) ^ (srow & 7);
  const __bf16* kbase = kp + ((long)b * SEQ) * DM + h * HD;
  const __bf16* vtb = vpT + (long)(h * HD) * M8 + (long)b * SEQ;

  auto stage = [&](int T, int sel) {
    const long kt = (long)T * 64;
    __bf16* Kd = &Ks[sel][(w * 8) * 64];
    __bf16* Vd = &Vs[sel][(w * 8) * 64];
    gload16(kbase + (kt + srow) * (long)DM + schunk * 8, Kd);
    gload16(kbase + (kt + 32 + srow) * (long)DM + schunk * 8, Kd + 32 * 64);
    gload16(vtb + (long)srow * M8 + kt + schunk * 8, Vd);
    gload16(vtb + (long)(32 + srow) * M8 + kt + schunk * 8, Vd + 32 * 64);
  };

  auto qk = [&](const __bf16* Kc, f32x16& s0, f32x16& s1, bool pv) {
    // kf reads issue first; PV (register-only) fills matrix pipe while they land
    bf16x8 kf[8];
#pragma unroll
    for (int kk = 0; kk < 4; ++kk) {
      const int sw = ((kk * 2 + hi) ^ (l31 & 7)) * 8;
      kf[kk]     = *(const bf16x8*)&Kc[l31 * 64 + sw];
      kf[4 + kk] = *(const bf16x8*)&Kc[2048 + l31 * 64 + sw];
    }
    __builtin_amdgcn_s_setprio(1);
    if (pv) {
#pragma unroll
      for (int ks = 0; ks < 4; ++ks) {
        o0 = mfma32(vfp[ks], pfp[ks], o0);
        o1 = mfma32(vfp[4 + ks], pfp[ks], o1);
      }
    }
#pragma unroll
    for (int kk = 0; kk < 4; ++kk) {
      s0 = mfma32(kf[kk], qf[kk], s0);
      s1 = mfma32(kf[4 + kk], qf[kk], s1);
    }
    __builtin_amdgcn_s_setprio(0);
  };

  auto load_v = [&](const __bf16* Vc) {
#pragma unroll
    for (int ks = 0; ks < 4; ++ks) {
      const int sw = ((ks * 2 + hi) ^ (l31 & 7)) * 8;
      vfp[ks]     = *(const bf16x8*)&Vc[l31 * 64 + sw];
      vfp[4 + ks] = *(const bf16x8*)&Vc[2048 + l31 * 64 + sw];
    }
  };

  auto softmax_pack = [&](f32x16& s0, f32x16& s1) {
#pragma unroll
    for (int r = 0; r < 16; ++r) s0[r] = exp2_(s0[r]);
#pragma unroll
    for (int r = 0; r < 16; ++r) s1[r] = exp2_(s1[r]);
    f32x16 ps = s0 + s1;
    const float t0 = (ps[0] + ps[1]) + (ps[2] + ps[3]);
    const float t1 = (ps[4] + ps[5]) + (ps[6] + ps[7]);
    const float t2 = (ps[8] + ps[9]) + (ps[10] + ps[11]);
    const float t3 = (ps[12] + ps[13]) + (ps[14] + ps[15]);
    lsum += (t0 + t1) + (t2 + t3);
#pragma unroll
    for (int ks = 0; ks < 4; ++ks) {
      const int base = 8 * (ks & 1);
      const f32x16& S = (ks < 2) ? s0 : s1;
      unsigned pa = pk(S[base + 0], S[base + 1]);
      unsigned pc = pk(S[base + 2], S[base + 3]);
      unsigned pb = pk(S[base + 4], S[base + 5]);
      unsigned pd = pk(S[base + 6], S[base + 7]);
      u32x2 r02 = pswap(pa, pb);
      u32x2 r13 = pswap(pc, pd);
      u32x4 pw;
      pw[0] = r02[0]; pw[1] = r13[0]; pw[2] = r02[1]; pw[3] = r13[1];
      pfp[ks] = __builtin_bit_cast(bf16x8, pw);
    }
  };

  stage(0, 0);
  stage(1, 1);
  __syncthreads();
  {  // iter 0: QK only (no PV yet); tiles 0,1 already resident
    f32x16 s0 = {}, s1 = {};
    qk(&Ks[0][0], s0, s1, false);
    load_v(&Vs[0][0]);
    softmax_pack(s0, s1);
    __syncthreads();   // all waves done with buffer 0 reads
  }
#pragma unroll 1
  for (int t = 1; t < SEQ / 64; ++t) {
    const int sel = t & 1;
    if (t + 1 < SEQ / 64) stage(t + 1, sel ^ 1);  // buffer sel^1 fully consumed
    f32x16 s0 = {}, s1 = {};
    qk(&Ks[sel][0], s0, s1, true);                // PV(t-1) + QK(t)
    load_v(&Vs[sel][0]);
    softmax_pack(s0, s1);
    __syncthreads();   // drains own DMAs + buffer handoff
  }
  {  // epilogue PV for last tile
    __builtin_amdgcn_s_setprio(1);
#pragma unroll
    for (int ks = 0; ks < 4; ++ks) {
      o0 = mfma32(vfp[ks], pfp[ks], o0);
      o1 = mfma32(vfp[4 + ks], pfp[ks], o1);
    }
    __builtin_amdgcn_s_setprio(0);
  }

  const float inv = 1.0f / pcomb_sum(lsum);
  __bf16* obase = ao + qrow * DM + h * HD;
#pragma unroll
  for (int rg = 0; rg < 4; ++rg) {
    bf16x4 v0, v1;
#pragma unroll
    for (int j = 0; j < 4; ++j) {
      v0[j] = (__bf16)(o0[rg * 4 + j] * inv);
      v1[j] = (__bf16)(o1[rg * 4 + j] * inv);
    }
    *(bf16x4*)(obase + 8 * rg + 4 * hi) = v0;
    *(bf16x4*)(obase + 32 + 8 * rg + 4 * hi) = v1;
  }
}

// ---------------- launch ----------------
extern "C" void kernel_launch(void* const* d_in, const int* in_sizes, int n_in,
                              void* d_out, int out_size, void* d_ws, size_t ws_size,
                              hipStream_t stream) {
  const float* q  = (const float*)d_in[0];
  const float* k  = (const float*)d_in[1];
  const float* v  = (const float*)d_in[2];
  const float* wq = (const float*)d_in[3];
  const float* bq = (const float*)d_in[4];
  const float* wk = (const float*)d_in[5];
  const float* bk = (const float*)d_in[6];
  const float* wv = (const float*)d_in[7];
  const float* bv = (const float*)d_in[8];
  const float* wo = (const float*)d_in[9];
  const float* bo = (const float*)d_in[10];

  const long S = (long)M8 * DM;   // 6291456
  const long W = (long)DM * DM;   // 589824
  __bf16* ws = (__bf16*)d_ws;
  __bf16 *wqb = ws, *wkb = wqb + W, *wvb = wkb + W, *wob = wvb + W;
  __bf16 *qpj = wob + W, *kpj = qpj + S, *vpT = kpj + S, *aob = vpT + S;

  cast4_kernel<<<dim3((unsigned)(W / 4 / 256), 4), 256, 0, stream>>>(
      wq, wk, wv, wo, wqb, wkb, wvb, wob, (int)(W / 4));

  proj3_gemm<<<1152, 256, 0, stream>>>(q, k, v, wqb, wkb, wvb, bq, bk, bv, qpj, kpj, vpT);

  attn_fwd<<<768, 256, 0, stream>>>(qpj, kpj, vpT, aob);

  out_gemm<<<768, 256, 0, stream>>>(aob, wob, bo, (float*)d_out);
}